// Round 15
// baseline (108.354 us; speedup 1.0000x reference)
//
#include <hip/hip_runtime.h>
#include <math.h>

// GTNormalLoss: kNN(k=10) PCA normals + cosine loss vs gt, mean over 8x4096 points.
// Round 15: collapse 4 launches -> 3. Fix kernel fused INTO scan: failing queries
// (bound/drop-detect) are re-solved inline by their own 8-lane group scanning the
// provable global window [qx+-hw] (L2-resident) with 10-deep sift + group butterfly.
// Per-block loss reduction -> partial[bid]; final reduce reads 2KB not 128KB.
// qloss / wsList / wsThr / wsCnt eliminated. R13 scan internals frozen.

#define NPTS   4096
#define KNN    10
#define KEEP   6
#define NBINS  256
#define XLO    (-5.5f)
#define INVBW  (256.0f / 11.0f)
#define W      1536
#define QPB    64
#define NB     512               // 8 batches * 64 chunks of 64 queries

__device__ __forceinline__ unsigned int umed3(unsigned int a, unsigned int b, unsigned int c) {
    unsigned int r;
    asm("v_med3_u32 %0, %1, %2, %3" : "=v"(r) : "v"(a), "v"(b), "v"(c));
    return r;
}

// insert key into ascending sorted nd[0..9], dropping old max; all static indexing.
__device__ __forceinline__ void sift(unsigned int nd[KNN], unsigned int key) {
#pragma unroll
    for (int t = KNN - 1; t >= 1; --t)
        nd[t] = umed3(key, nd[t - 1], nd[t]);
    nd[0] = nd[0] < key ? nd[0] : key;
}

// 6-deep variant for the slice-local scan loop.
__device__ __forceinline__ void sift6(unsigned int nd[KEEP], unsigned int key) {
#pragma unroll
    for (int t = KEEP - 1; t >= 1; --t)
        nd[t] = umed3(key, nd[t - 1], nd[t]);
    nd[0] = nd[0] < key ? nd[0] : key;
}

__device__ __forceinline__ int xbin(float x) {
    int bin = (int)floorf((x - XLO) * INVBW);
    return bin < 0 ? 0 : (bin > NBINS - 1 ? NBINS - 1 : bin);
}

// ---- epilogue (f32): PCA normal from 10 neighbors -> 1-cos loss vs gt ----
__device__ float normal_loss3f(const float nbx[KNN], const float nby[KNN],
                               const float nbz[KNN], const float* g3)
{
    float sx = 0.f, sy = 0.f, sz = 0.f;
#pragma unroll
    for (int t = 0; t < KNN; ++t) { sx += nbx[t]; sy += nby[t]; sz += nbz[t]; }
    float mx = sx * 0.1f, my = sy * 0.1f, mz = sz * 0.1f;
    float c00 = 0.f, c01 = 0.f, c02 = 0.f, c11 = 0.f, c12 = 0.f, c22 = 0.f;
#pragma unroll
    for (int t = 0; t < KNN; ++t) {
        float ux = nbx[t] - mx, uy = nby[t] - my, uz = nbz[t] - mz;
        c00 = fmaf(ux, ux, c00);
        c01 = fmaf(ux, uy, c01);
        c02 = fmaf(ux, uz, c02);
        c11 = fmaf(uy, uy, c11);
        c12 = fmaf(uy, uz, c12);
        c22 = fmaf(uz, uz, c22);
    }
    float a00 = c00 * 0.1f, a01 = c01 * 0.1f, a02 = c02 * 0.1f;
    float a11 = c11 * 0.1f, a12 = c12 * 0.1f, a22 = c22 * 0.1f;

    float vx = 1.0f, vy = 0.0f, vz = 0.0f;
    float qd = (a00 + a11 + a22) * (1.0f / 3.0f);
    float p1 = a01 * a01 + a02 * a02 + a12 * a12;
    float b00 = a00 - qd, b11 = a11 - qd, b22 = a22 - qd;
    float p2 = b00 * b00 + b11 * b11 + b22 * b22 + 2.0f * p1;
    if (p2 > 1e-30f) {
        float p   = sqrtf(p2 * (1.0f / 6.0f));
        float inv = 1.0f / p;
        float m00 = b00 * inv, m01 = a01 * inv, m02 = a02 * inv;
        float m11 = b11 * inv, m12 = a12 * inv, m22 = b22 * inv;
        float detB = m00 * (m11 * m22 - m12 * m12)
                   - m01 * (m01 * m22 - m12 * m02)
                   + m02 * (m01 * m12 - m11 * m02);
        float r = 0.5f * detB;
        r = r < -1.0f ? -1.0f : (r > 1.0f ? 1.0f : r);
        float phi  = acosf(r) * (1.0f / 3.0f);
        float eig0 = qd + 2.0f * p * cosf(phi + 2.0943951023931953f); // smallest
        float r0x = a00 - eig0, r0y = a01, r0z = a02;
        float r1y = a11 - eig0, r1z = a12;
        float r2z = a22 - eig0;
        float c0x = r0y * r1z - r0z * r1y;
        float c0y = r0z * r0y - r0x * r1z;
        float c0z = r0x * r1y - r0y * r0y;
        float c1x = r0y * r2z - r0z * r1z;
        float c1y = r0z * r0z - r0x * r2z;
        float c1z = r0x * r1z - r0y * r0z;
        float c2x = r1y * r2z - r1z * r1z;
        float c2y = r1z * r0z - r0y * r2z;
        float c2z = r0y * r1z - r1y * r0z;
        float n0 = c0x * c0x + c0y * c0y + c0z * c0z;
        float n1 = c1x * c1x + c1y * c1y + c1z * c1z;
        float n2 = c2x * c2x + c2y * c2y + c2z * c2z;
        float bx, by, bz, bn;
        if (n0 >= n1 && n0 >= n2) { bx = c0x; by = c0y; bz = c0z; bn = n0; }
        else if (n1 >= n2)        { bx = c1x; by = c1y; bz = c1z; bn = n1; }
        else                      { bx = c2x; by = c2y; bz = c2z; bn = n2; }
        if (bn > 1e-30f) {
            float s = rsqrtf(bn);
            vx = bx * s; vy = by * s; vz = bz * s;
        }
    }
    float gx = g3[0], gy = g3[1], gz = g3[2];
    float dotg = vx * gx + vy * gy + vz * gz;
    float na = sqrtf(vx * vx + vy * vy + vz * vz);
    float gn = sqrtf(gx * gx + gy * gy + gz * gz);
    float cs = dotg / (fmaxf(na, 1e-8f) * fmaxf(gn, 1e-8f));
    return 1.0f - cs;
}

// ---- kernel 1: counting-sort each batch's points by x (1024 threads);
//      w of each staged point = original index bits; writes bin table ----
__global__ __launch_bounds__(1024) void gtnl_bin(
    const float* __restrict__ pred, float4* __restrict__ wsPts,
    unsigned int* __restrict__ wsBins)
{
    __shared__ unsigned int hist[NBINS];
    __shared__ unsigned int bst[NBINS + 1];

    const int tid = threadIdx.x;
    const int b   = blockIdx.x;
    const float* src = pred + (size_t)b * NPTS * 3;

    if (tid < NBINS) hist[tid] = 0;
    __syncthreads();

    float px[4], py[4], pz[4];
    int   pb[4], pidx[4];
#pragma unroll
    for (int k = 0; k < 4; ++k) {
        int p = tid + 1024 * k;
        float x = src[3 * p + 0];
        float y = src[3 * p + 1];
        float z = src[3 * p + 2];
        int bin = xbin(x);
        px[k] = x; py[k] = y; pz[k] = z; pb[k] = bin; pidx[k] = p;
        atomicAdd(&hist[bin], 1u);
    }
    __syncthreads();

    if (tid < 64) {
        unsigned s0 = hist[4 * tid + 0], s1 = hist[4 * tid + 1];
        unsigned s2 = hist[4 * tid + 2], s3 = hist[4 * tid + 3];
        unsigned tot = s0 + s1 + s2 + s3;
        unsigned pre = tot;
#pragma unroll
        for (int d = 1; d < 64; d <<= 1) {
            unsigned t = __shfl_up(pre, d, 64);
            if (tid >= d) pre += t;
        }
        unsigned ex = pre - tot;
        bst[4 * tid + 0] = ex;
        bst[4 * tid + 1] = ex + s0;
        bst[4 * tid + 2] = ex + s0 + s1;
        bst[4 * tid + 3] = ex + s0 + s1 + s2;
        if (tid == 63) bst[NBINS] = ex + tot;    // == NPTS
    }
    __syncthreads();

    if (tid < NBINS) hist[tid] = bst[tid];
    __syncthreads();

#pragma unroll
    for (int k = 0; k < 4; ++k) {
        unsigned pos = atomicAdd(&hist[pb[k]], 1u);
        wsPts[(size_t)b * NPTS + pos] =
            make_float4(px[k], py[k], pz[k], __uint_as_float((unsigned)pidx[k]));
    }
    if (tid < NBINS) wsBins[b * (NBINS + 1) + tid] = bst[tid];
    if (tid == 0)    wsBins[b * (NBINS + 1) + NBINS] = bst[NBINS];
}

// ---- kernel 2: window scan + INLINE exact fix + per-block loss reduction ----
__global__ __launch_bounds__(512, 4) void gtnl_scan(
    const float4* __restrict__ wsPts, const unsigned int* __restrict__ wsBins,
    const float* __restrict__ gt, float* __restrict__ partial)
{
    __shared__ float4 pts[W];                    // 24 KB (w = orig index bits)
    __shared__ float rbuf[512];

    const int tid   = threadIdx.x;
    const int bid   = blockIdx.x;
    const int b     = bid >> 6;                  // 64 chunks per batch
    const int chunk = bid & 63;
    const int qbase = chunk * QPB;
    const int s     = tid & 7;                   // slice 0..7 (adjacent lanes)
    const int ql    = tid >> 3;                  // query 0..63

    int W0 = qbase + QPB / 2 - W / 2;
    W0 = W0 < 0 ? 0 : (W0 > NPTS - W ? NPTS - W : W0);

    const float4* wp = wsPts + (size_t)b * NPTS;
    for (int i = tid; i < W; i += 512) pts[i] = wp[W0 + i];   // plain copy
    __syncthreads();

    const int qpos = qbase + ql;                 // sorted index of my query
    const float4 q = pts[qpos - W0];

    unsigned int nd6[KEEP];
#pragma unroll
    for (int t = 0; t < KEEP; ++t) nd6[t] = 0x7F000000u;     // huge finite sentinel

    int j = s;
#pragma unroll 8
    for (int t = 0; t < W / 8; ++t, j += 8) {    // 192 static trips
        float4 c = pts[j];
        float dx = q.x - c.x, dy = q.y - c.y, dz = q.z - c.z;
        float d  = fmaf(dx, dx, fmaf(dy, dy, dz * dz));      // >= 0 by construction
        unsigned int key = (__float_as_uint(d) & 0xFFFFF000u) | (unsigned)j;
        sift6(nd6, key);
    }
    const unsigned int kmin6 = nd6[KEEP - 1];    // slice kept-min (pre-merge)

    // expand to 10-deep and butterfly-merge across the 8 slices
    unsigned int nd[KNN];
#pragma unroll
    for (int t = 0; t < KEEP; ++t) nd[t] = nd6[t];
#pragma unroll
    for (int t = KEEP; t < KNN; ++t) nd[t] = 0x7F000000u;
#pragma unroll
    for (int r = 1; r <= 4; r <<= 1) {
        unsigned int tmp[KNN];
#pragma unroll
        for (int t = 0; t < KNN; ++t) tmp[t] = nd[t];
#pragma unroll
        for (int t = 0; t < KNN; ++t) {
            unsigned int pk = (unsigned int)__shfl_xor((int)tmp[t], r, 64);
            sift(nd, pk);
        }
    }

    // drop-detection: if any slice's kept-min < merged nd[9], a true top-10 key
    // may have been dropped (keys unique) -> inline exact fix. Else provably exact.
    unsigned int sok = (kmin6 > nd[KNN - 1]) ? 1u : 0u;
#pragma unroll
    for (int r = 1; r <= 4; r <<= 1) sok &= (unsigned int)__shfl_xor((int)sok, r, 64);

    // window-edge exclusion bound (merged nd[9] >= true d10 -> conservative)
    unsigned int thr_bits = (nd[KNN - 1] & 0xFFFFF000u) + 0x1000u;
    float thr = __uint_as_float(thr_bits);
    float hw  = __uint_as_float(__float_as_uint(sqrtf(thr)) + 4) + 1e-3f;
    bool okL = (W0 == 0)        || (q.x - hw > pts[0].x);
    bool okR = (W0 == NPTS - W) || (q.x + hw < pts[W - 1].x);
    const bool ok = okL && okR && (sok != 0u);

    if (!ok) {
        // ---- inline exact fix: this query's 8 lanes rescan the provable
        // window [qx-hw, qx+hw] from global (L2-resident), 10-deep sift ----
        const unsigned int* bst = wsBins + b * (NBINS + 1);
        const int jlo = (int)bst[xbin(q.x - hw)];
        const int jhi = (int)bst[xbin(q.x + hw) + 1];

#pragma unroll
        for (int t = 0; t < KNN; ++t) nd[t] = 0x7F000000u;
        for (int j0 = jlo + s; j0 < jhi; j0 += 8) {
            float4 v = wp[j0];
            float dx = q.x - v.x, dy = q.y - v.y, dz = q.z - v.z;
            float d  = fmaf(dx, dx, fmaf(dy, dy, dz * dz));
            sift(nd, (__float_as_uint(d) & 0xFFFFF000u) | (unsigned)j0);
        }
#pragma unroll
        for (int r = 1; r <= 4; r <<= 1) {
            unsigned int tmp[KNN];
#pragma unroll
            for (int t = 0; t < KNN; ++t) tmp[t] = nd[t];
#pragma unroll
            for (int t = 0; t < KNN; ++t) {
                unsigned int pk = (unsigned int)__shfl_xor((int)tmp[t], r, 64);
                sift(nd, pk);
            }
        }
    }

    // gather neighbors (pass: from LDS window; fix: from global sorted array)
    float nbx[KNN], nby[KNN], nbz[KNN];
    if (ok) {
#pragma unroll
        for (int t = 0; t < KNN; ++t) {
            float4 pn = pts[nd[t] & 0xFFFu];
            nbx[t] = pn.x; nby[t] = pn.y; nbz[t] = pn.z;
        }
    } else {
#pragma unroll
        for (int t = 0; t < KNN; ++t) {
            float4 pn = wp[nd[t] & 0xFFFu];
            nbx[t] = pn.x; nby[t] = pn.y; nbz[t] = pn.z;
        }
    }
    const unsigned int qorig = __float_as_uint(q.w);
    float res = normal_loss3f(nbx, nby, nbz, gt + ((size_t)b * NPTS + qorig) * 3);

    // deterministic block reduction of the 64 per-query losses
    rbuf[tid] = (s == 0) ? res : 0.0f;
    __syncthreads();
    for (int k = 256; k > 0; k >>= 1) {
        if (tid < k) rbuf[tid] += rbuf[tid + k];
        __syncthreads();
    }
    if (tid == 0) partial[bid] = rbuf[0];
}

// ---- kernel 3: sum 512 block partials ----
__global__ __launch_bounds__(512) void gtnl_reduceP(
    const float* __restrict__ partial, float* __restrict__ out)
{
    __shared__ float sb[512];
    const int tid = threadIdx.x;
    sb[tid] = partial[tid];
    __syncthreads();
    for (int k = 256; k > 0; k >>= 1) {
        if (tid < k) sb[tid] += sb[tid + k];
        __syncthreads();
    }
    if (tid == 0) out[0] = sb[0] / 32768.0f;
}

// ---- fallback: R2 brute force (used when ws_size is too small) ----
__global__ __launch_bounds__(256) void gtnl_brute(
    const float* __restrict__ pred, const float* __restrict__ gt,
    float* __restrict__ partial)
{
    __shared__ float4 ptsB[NPTS];
    __shared__ unsigned int mbuf[64][3][KNN];

    const int tid = threadIdx.x;
    const int b   = blockIdx.x >> 6;
    const int qc  = blockIdx.x & 63;
    const int ql  = tid & 63;
    const int sub = tid >> 6;
    const int qi  = qc * 64 + ql;

    const float* src = pred + (size_t)b * NPTS * 3;
    for (int p = tid; p < NPTS; p += 256) {
        float x = src[3 * p + 0], y = src[3 * p + 1], z = src[3 * p + 2];
        ptsB[p] = make_float4(x, y, z, 0.0f);
    }
    __syncthreads();

    const float4 q = ptsB[qi];
    unsigned int nd[KNN];
#pragma unroll
    for (int t = 0; t < KNN; ++t) nd[t] = 0xFFFFFFFFu;

    const int j0 = sub * 1024;
#pragma unroll 8
    for (int j = j0; j < j0 + 1024; ++j) {
        float4 c = ptsB[j];
        float dx = q.x - c.x, dy = q.y - c.y, dz = q.z - c.z;
        float d  = fmaf(dx, dx, fmaf(dy, dy, dz * dz));
        sift(nd, (__float_as_uint(d) & 0xFFFFF000u) | (unsigned)j);
    }

    if (sub != 0) {
#pragma unroll
        for (int t = 0; t < KNN; ++t) mbuf[ql][sub - 1][t] = nd[t];
    }
    __syncthreads();

    float res = 0.0f;
    if (sub == 0) {
#pragma unroll
        for (int ss = 0; ss < 3; ++ss)
#pragma unroll
            for (int t = 0; t < KNN; ++t) sift(nd, mbuf[ql][ss][t]);
        float nbx[KNN], nby[KNN], nbz[KNN];
#pragma unroll
        for (int t = 0; t < KNN; ++t) {
            float4 pn = ptsB[nd[t] & 0xFFFu];
            nbx[t] = pn.x; nby[t] = pn.y; nbz[t] = pn.z;
        }
        res = normal_loss3f(nbx, nby, nbz, gt + ((size_t)b * NPTS + qi) * 3);
#pragma unroll
        for (int d = 32; d > 0; d >>= 1) res += __shfl_xor(res, d, 64);
    }
    __syncthreads();
    if (tid == 0) partial[blockIdx.x] = res;
}

extern "C" void kernel_launch(void* const* d_in, const int* in_sizes, int n_in,
                              void* d_out, int out_size, void* d_ws, size_t ws_size,
                              hipStream_t stream) {
    const float* pred = (const float*)d_in[0];
    const float* gt   = (const float*)d_in[1];
    float* out        = (float*)d_out;

    const size_t PTS_BYTES  = (size_t)8 * NPTS * sizeof(float4);          // 524288
    const size_t BINS_BYTES = (size_t)8 * (NBINS + 1) * sizeof(unsigned); // 8224
    const size_t PART_BYTES = (size_t)NB * sizeof(float);                 // 2048
    const size_t NEED = PTS_BYTES + BINS_BYTES + PART_BYTES;

    if (ws_size >= NEED) {
        char* p = (char*)d_ws;
        float4*       wsPts  = (float4*)p;                 p += PTS_BYTES;
        unsigned int* wsBins = (unsigned int*)p;           p += BINS_BYTES;
        float*        partial= (float*)p;

        gtnl_bin<<<8, 1024, 0, stream>>>(pred, wsPts, wsBins);
        gtnl_scan<<<NB, 512, 0, stream>>>(wsPts, wsBins, gt, partial);
        gtnl_reduceP<<<1, NB, 0, stream>>>(partial, out);
    } else {
        float* partial = (float*)d_ws;   // 512 floats
        gtnl_brute<<<512, 256, 0, stream>>>(pred, gt, partial);
        gtnl_reduceP<<<1, 512, 0, stream>>>(partial, out);
    }
}

// Round 16
// 53.846 us; speedup vs baseline: 2.0123x; 2.0123x over previous
//
#include <hip/hip_runtime.h>
#include <math.h>

// GTNormalLoss: kNN(k=10) PCA normals + cosine loss vs gt, mean over 8x4096 points.
// Round 16: REVERT to R9 (best measured: 53.9us), plus R14's free robustness clamp
// in gtnl_fix. History: R6-R15 tried occupancy (R10), pruning (R11), per-pair cost
// (R13), block-size (R14), launch fusion (R8: cross-XCD fence disaster; R15:
// branch-merged arrays -> scratch disaster). Four distinct designs all land at
// 53.9-54.8us: scan is VALU/LDS co-saturated (~30us) + ~25us orchestration floor.

#define NPTS   4096
#define KNN    10
#define NBINS  256
#define XLO    (-5.5f)
#define INVBW  (256.0f / 11.0f)
#define W      1536
#define QPB    32
#define NB     1024              // 8 batches * 128 chunks of 32 queries
#define LISTCAP 32768

__device__ __forceinline__ unsigned int umed3(unsigned int a, unsigned int b, unsigned int c) {
    unsigned int r;
    asm("v_med3_u32 %0, %1, %2, %3" : "=v"(r) : "v"(a), "v"(b), "v"(c));
    return r;
}

// insert key into ascending sorted nd[0..9], dropping old max; all static indexing.
__device__ __forceinline__ void sift(unsigned int nd[KNN], unsigned int key) {
#pragma unroll
    for (int t = KNN - 1; t >= 1; --t)
        nd[t] = umed3(key, nd[t - 1], nd[t]);
    nd[0] = nd[0] < key ? nd[0] : key;
}

__device__ __forceinline__ int xbin(float x) {
    int bin = (int)floorf((x - XLO) * INVBW);
    return bin < 0 ? 0 : (bin > NBINS - 1 ? NBINS - 1 : bin);
}

#define MAKE_KEY(q, c, J)                                                     \
    ({                                                                        \
        float sw_ = (q).w + (c).w;                                            \
        float dp_ = fmaf((q).x, (c).x, fmaf((q).y, (c).y, (q).z * (c).z));    \
        float d_  = fmaf(-2.0f, dp_, sw_);                                    \
        d_ = fmaxf(d_, 0.0f);                                                 \
        (__float_as_uint(d_) & 0xFFFFF000u) | (unsigned)(J);                  \
    })

// ---- epilogue: PCA normal from 10 neighbors -> 1-cos loss vs gt (f64 core) ----
__device__ float normal_loss3(const float nbx[KNN], const float nby[KNN],
                              const float nbz[KNN], const float* g3)
{
    float sx = 0.f, sy = 0.f, sz = 0.f;
#pragma unroll
    for (int t = 0; t < KNN; ++t) { sx += nbx[t]; sy += nby[t]; sz += nbz[t]; }
    float mx = sx / 10.0f, my = sy / 10.0f, mz = sz / 10.0f;
    float c00 = 0.f, c01 = 0.f, c02 = 0.f, c11 = 0.f, c12 = 0.f, c22 = 0.f;
#pragma unroll
    for (int t = 0; t < KNN; ++t) {
        float ux = nbx[t] - mx, uy = nby[t] - my, uz = nbz[t] - mz;
        c00 = fmaf(ux, ux, c00);
        c01 = fmaf(ux, uy, c01);
        c02 = fmaf(ux, uz, c02);
        c11 = fmaf(uy, uy, c11);
        c12 = fmaf(uy, uz, c12);
        c22 = fmaf(uz, uz, c22);
    }
    double a00 = (double)(c00 / 10.0f), a01 = (double)(c01 / 10.0f);
    double a02 = (double)(c02 / 10.0f), a11 = (double)(c11 / 10.0f);
    double a12 = (double)(c12 / 10.0f), a22 = (double)(c22 / 10.0f);

    double vx = 1.0, vy = 0.0, vz = 0.0;
    double qd = (a00 + a11 + a22) / 3.0;
    double p1 = a01 * a01 + a02 * a02 + a12 * a12;
    double b00 = a00 - qd, b11 = a11 - qd, b22 = a22 - qd;
    double p2 = b00 * b00 + b11 * b11 + b22 * b22 + 2.0 * p1;
    if (p2 > 1e-300) {
        double p = sqrt(p2 / 6.0);
        double inv = 1.0 / p;
        double m00 = b00 * inv, m01 = a01 * inv, m02 = a02 * inv;
        double m11 = b11 * inv, m12 = a12 * inv, m22 = b22 * inv;
        double detB = m00 * (m11 * m22 - m12 * m12)
                    - m01 * (m01 * m22 - m12 * m02)
                    + m02 * (m01 * m12 - m11 * m02);
        double r = 0.5 * detB;
        r = r < -1.0 ? -1.0 : (r > 1.0 ? 1.0 : r);
        double phi = acos(r) / 3.0;
        double eig0 = qd + 2.0 * p * cos(phi + 2.0943951023931953); // smallest
        double r0x = a00 - eig0, r0y = a01, r0z = a02;
        double r1y = a11 - eig0, r1z = a12;
        double r2z = a22 - eig0;
        double c0x = r0y * r1z - r0z * r1y;
        double c0y = r0z * r0y - r0x * r1z;
        double c0z = r0x * r1y - r0y * r0y;
        double c1x = r0y * r2z - r0z * r1z;
        double c1y = r0z * r0z - r0x * r2z;
        double c1z = r0x * r1z - r0y * r0z;
        double c2x = r1y * r2z - r1z * r1z;
        double c2y = r1z * r0z - r0y * r2z;
        double c2z = r0y * r1z - r1y * r0z;
        double n0 = c0x * c0x + c0y * c0y + c0z * c0z;
        double n1 = c1x * c1x + c1y * c1y + c1z * c1z;
        double n2 = c2x * c2x + c2y * c2y + c2z * c2z;
        double bx, by, bz, bn;
        if (n0 >= n1 && n0 >= n2) { bx = c0x; by = c0y; bz = c0z; bn = n0; }
        else if (n1 >= n2)        { bx = c1x; by = c1y; bz = c1z; bn = n1; }
        else                      { bx = c2x; by = c2y; bz = c2z; bn = n2; }
        if (bn > 1e-300) {
            double s = 1.0 / sqrt(bn);
            vx = bx * s; vy = by * s; vz = bz * s;
        }
    }
    float nx = (float)vx, ny = (float)vy, nz = (float)vz;
    float gx = g3[0], gy = g3[1], gz = g3[2];
    float dotg = nx * gx + ny * gy + nz * gz;
    float na = sqrtf(nx * nx + ny * ny + nz * nz);
    float gn = sqrtf(gx * gx + gy * gy + gz * gz);
    float cs = dotg / (fmaxf(na, 1e-8f) * fmaxf(gn, 1e-8f));
    return 1.0f - cs;
}

// ---- kernel 1: counting-sort each batch's points by x (1024 threads) ----
__global__ __launch_bounds__(1024) void gtnl_bin(
    const float* __restrict__ pred, float4* __restrict__ wsPts,
    unsigned int* __restrict__ wsCnt)
{
    __shared__ unsigned int hist[NBINS];
    __shared__ unsigned int bst[NBINS + 1];

    const int tid = threadIdx.x;
    const int b   = blockIdx.x;
    if (b == 0 && tid == 0) wsCnt[0] = 0;
    const float* src = pred + (size_t)b * NPTS * 3;

    if (tid < NBINS) hist[tid] = 0;
    __syncthreads();

    float px[4], py[4], pz[4];
    int   pb[4], pidx[4];
#pragma unroll
    for (int k = 0; k < 4; ++k) {
        int p = tid + 1024 * k;
        float x = src[3 * p + 0];
        float y = src[3 * p + 1];
        float z = src[3 * p + 2];
        int bin = xbin(x);
        px[k] = x; py[k] = y; pz[k] = z; pb[k] = bin; pidx[k] = p;
        atomicAdd(&hist[bin], 1u);
    }
    __syncthreads();

    if (tid < 64) {
        unsigned s0 = hist[4 * tid + 0], s1 = hist[4 * tid + 1];
        unsigned s2 = hist[4 * tid + 2], s3 = hist[4 * tid + 3];
        unsigned tot = s0 + s1 + s2 + s3;
        unsigned pre = tot;
#pragma unroll
        for (int d = 1; d < 64; d <<= 1) {
            unsigned t = __shfl_up(pre, d, 64);
            if (tid >= d) pre += t;
        }
        unsigned ex = pre - tot;
        bst[4 * tid + 0] = ex;
        bst[4 * tid + 1] = ex + s0;
        bst[4 * tid + 2] = ex + s0 + s1;
        bst[4 * tid + 3] = ex + s0 + s1 + s2;
        if (tid == 63) bst[NBINS] = ex + tot;
    }
    __syncthreads();

    if (tid < NBINS) hist[tid] = bst[tid];
    __syncthreads();

#pragma unroll
    for (int k = 0; k < 4; ++k) {
        unsigned pos = atomicAdd(&hist[pb[k]], 1u);
        wsPts[(size_t)b * NPTS + pos] =
            make_float4(px[k], py[k], pz[k], __uint_as_float((unsigned)pidx[k]));
    }
}

// ---- kernel 2: uniform fixed-window scan, per-query bound check ----
__global__ __launch_bounds__(256, 4) void gtnl_scan(
    const float4* __restrict__ wsPts, const float* __restrict__ gt,
    float* __restrict__ qloss, unsigned int* __restrict__ wsCnt,
    unsigned int* __restrict__ wsList)
{
    __shared__ float4 pts[W];                    // 24 KB (w = |p|^2)
    __shared__ unsigned int mbuf[7][QPB][KNN];   // 8.75 KB

    const int tid   = threadIdx.x;
    const int bid   = blockIdx.x;
    const int b     = bid >> 7;                  // 128 chunks per batch
    const int chunk = bid & 127;
    const int qbase = chunk * QPB;
    const int s     = tid >> 5;                  // slice 0..7 (8 threads/query)
    const int ql    = tid & 31;

    int W0 = qbase + QPB / 2 - W / 2;
    W0 = W0 < 0 ? 0 : (W0 > NPTS - W ? NPTS - W : W0);

    const float4* wp = wsPts + (size_t)b * NPTS;
    for (int i = tid; i < W; i += 256) {
        float4 v = wp[W0 + i];
        pts[i] = make_float4(v.x, v.y, v.z, fmaf(v.x, v.x, fmaf(v.y, v.y, v.z * v.z)));
    }
    __syncthreads();

    const int qpos = qbase + ql;                 // sorted index of my query
    const float4 q = pts[qpos - W0];

    unsigned int nd[KNN];
#pragma unroll
    for (int t = 0; t < KNN; ++t) nd[t] = 0x7F000000u;   // huge finite sentinel

#pragma unroll 8
    for (int t = 0; t < W / 8; ++t) {            // 192 static trips
        int j = 8 * t + s;
        float4 c = pts[j];
        sift(nd, MAKE_KEY(q, c, j));
    }

    if (s != 0) {
#pragma unroll
        for (int t = 0; t < KNN; ++t) mbuf[s - 1][ql][t] = nd[t];
    }
    __syncthreads();
    if (s != 0) return;

    // merge 7 partner lists (disjoint slices -> exact window top-10)
#pragma unroll
    for (int m = 0; m < 7; ++m)
#pragma unroll
        for (int t = 0; t < KNN; ++t) sift(nd, mbuf[m][ql][t]);

    // provable exclusion bound: points left/right of window are at least
    // (q.x - edge_x)^2 away; conservative slack for truncation + fp formula noise.
    unsigned int thr_bits = (nd[KNN - 1] & 0xFFFFF000u) + 0x1000u;
    float thr = __uint_as_float(thr_bits);
    float hw  = __uint_as_float(__float_as_uint(sqrtf(thr)) + 4) + 1e-3f;
    bool okL = (W0 == 0)        || (q.x - hw > pts[0].x);
    bool okR = (W0 == NPTS - W) || (q.x + hw < pts[W - 1].x);

    const unsigned int qorig = __float_as_uint(wp[qpos].w);
    float res = 0.0f;
    if (okL && okR) {
        float nbx[KNN], nby[KNN], nbz[KNN];
#pragma unroll
        for (int t = 0; t < KNN; ++t) {
            float4 pn = pts[nd[t] & 0xFFFu];
            nbx[t] = pn.x; nby[t] = pn.y; nbz[t] = pn.z;
        }
        res = normal_loss3(nbx, nby, nbz, gt + ((size_t)b * NPTS + qorig) * 3);
    } else {
        unsigned int idx = atomicAdd(wsCnt, 1u);
        if (idx < LISTCAP) wsList[idx] = ((unsigned)b << 12) | (unsigned)qpos;
    }
    qloss[(size_t)b * NPTS + qorig] = res;
}

// ---- kernel 3: exact cleanup, one wave per flagged query, full 4096 scan ----
__global__ __launch_bounds__(256, 4) void gtnl_fix(
    const float4* __restrict__ wsPts, const float* __restrict__ gt,
    float* __restrict__ qloss, const unsigned int* __restrict__ wsCnt,
    const unsigned int* __restrict__ wsList)
{
    const int lane = threadIdx.x & 63;
    const int wid  = blockIdx.x * 4 + (threadIdx.x >> 6);   // 4096 waves
    unsigned int n = wsCnt[0];
    n = n < LISTCAP ? n : LISTCAP;               // robustness clamp (R14)

    for (unsigned int i = wid; i < n; i += 4096) {
        unsigned int e = wsList[i];
        const int b    = e >> 12;
        const int qpos = e & 0xFFF;
        const float4* wp = wsPts + (size_t)b * NPTS;

        float4 qv = wp[qpos];
        float4 q  = make_float4(qv.x, qv.y, qv.z,
                                fmaf(qv.x, qv.x, fmaf(qv.y, qv.y, qv.z * qv.z)));
        const unsigned int qorig = __float_as_uint(qv.w);

        unsigned int nd[KNN];
#pragma unroll
        for (int t = 0; t < KNN; ++t) nd[t] = 0x7F000000u;

#pragma unroll 8
        for (int t = 0; t < NPTS / 64; ++t) {    // 64 coalesced trips
            int j = 64 * t + lane;
            float4 v = wp[j];
            float4 c = make_float4(v.x, v.y, v.z,
                                   fmaf(v.x, v.x, fmaf(v.y, v.y, v.z * v.z)));
            sift(nd, MAKE_KEY(q, c, j));
        }

        // extract wave-global top-10 (keys unique: index in low bits)
        unsigned int keys[KNN];
#pragma unroll
        for (int r = 0; r < KNN; ++r) {
            unsigned int m = nd[0];
#pragma unroll
            for (int d = 1; d < 64; d <<= 1) {
                unsigned int o = __shfl_xor(m, d, 64);
                m = m < o ? m : o;
            }
            keys[r] = m;
            bool win = (nd[0] == m);
#pragma unroll
            for (int t = 0; t < KNN - 1; ++t) nd[t] = win ? nd[t + 1] : nd[t];
            nd[KNN - 1] = win ? 0xFFFFFFFFu : nd[KNN - 1];
        }

        float nbx[KNN], nby[KNN], nbz[KNN];
#pragma unroll
        for (int t = 0; t < KNN; ++t) {
            float4 pn = wp[keys[t] & 0xFFFu];
            nbx[t] = pn.x; nby[t] = pn.y; nbz[t] = pn.z;
        }
        float res = normal_loss3(nbx, nby, nbz, gt + ((size_t)b * NPTS + qorig) * 3);
        if (lane == 0) qloss[(size_t)b * NPTS + qorig] = res;
    }
}

// ---- kernel 4: sum 32768 per-query losses ----
__global__ __launch_bounds__(1024) void gtnl_reduceQ(
    const float* __restrict__ qloss, float* __restrict__ out)
{
    __shared__ float sbuf[1024];
    const int tid = threadIdx.x;
    const float4* q4 = (const float4*)qloss;
    float s = 0.0f;
#pragma unroll
    for (int t = 0; t < 8; ++t) {
        float4 v = q4[tid + 1024 * t];
        s += (v.x + v.y) + (v.z + v.w);
    }
    sbuf[tid] = s;
    __syncthreads();
    for (int k = 512; k > 0; k >>= 1) {
        if (tid < k) sbuf[tid] += sbuf[tid + k];
        __syncthreads();
    }
    if (tid == 0) out[0] = sbuf[0] / 32768.0f;
}

// ---- fallback: R2 brute force (used when ws_size is too small) ----
__global__ __launch_bounds__(256) void gtnl_brute(
    const float* __restrict__ pred, const float* __restrict__ gt,
    float* __restrict__ partial)
{
    __shared__ float4 ptsB[NPTS];
    __shared__ unsigned int mbuf[64][3][KNN];

    const int tid = threadIdx.x;
    const int b   = blockIdx.x >> 6;
    const int qc  = blockIdx.x & 63;
    const int ql  = tid & 63;
    const int sub = tid >> 6;
    const int qi  = qc * 64 + ql;

    const float* src = pred + (size_t)b * NPTS * 3;
    for (int p = tid; p < NPTS; p += 256) {
        float x = src[3 * p + 0], y = src[3 * p + 1], z = src[3 * p + 2];
        ptsB[p] = make_float4(x, y, z, fmaf(x, x, fmaf(y, y, z * z)));
    }
    __syncthreads();

    const float4 q = ptsB[qi];
    unsigned int nd[KNN];
#pragma unroll
    for (int t = 0; t < KNN; ++t) nd[t] = 0xFFFFFFFFu;

    const int j0 = sub * 1024;
#pragma unroll 8
    for (int j = j0; j < j0 + 1024; ++j) {
        float4 c = ptsB[j];
        sift(nd, MAKE_KEY(q, c, j));
    }

    if (sub != 0) {
#pragma unroll
        for (int t = 0; t < KNN; ++t) mbuf[ql][sub - 1][t] = nd[t];
    }
    __syncthreads();

    float res = 0.0f;
    if (sub == 0) {
#pragma unroll
        for (int ss = 0; ss < 3; ++ss)
#pragma unroll
            for (int t = 0; t < KNN; ++t) sift(nd, mbuf[ql][ss][t]);
        float nbx[KNN], nby[KNN], nbz[KNN];
#pragma unroll
        for (int t = 0; t < KNN; ++t) {
            float4 pn = ptsB[nd[t] & 0xFFFu];
            nbx[t] = pn.x; nby[t] = pn.y; nbz[t] = pn.z;
        }
        res = normal_loss3(nbx, nby, nbz, gt + ((size_t)b * NPTS + qi) * 3);
#pragma unroll
        for (int d = 32; d > 0; d >>= 1) res += __shfl_xor(res, d, 64);
    }
    __syncthreads();
    if (tid == 0) partial[blockIdx.x] = res;
}

__global__ __launch_bounds__(512) void gtnl_reduceP(
    const float* __restrict__ partial, float* __restrict__ out)
{
    __shared__ float sb[512];
    const int tid = threadIdx.x;
    sb[tid] = partial[tid];
    __syncthreads();
    for (int k = 256; k > 0; k >>= 1) {
        if (tid < k) sb[tid] += sb[tid + k];
        __syncthreads();
    }
    if (tid == 0) out[0] = sb[0] / 32768.0f;
}

extern "C" void kernel_launch(void* const* d_in, const int* in_sizes, int n_in,
                              void* d_out, int out_size, void* d_ws, size_t ws_size,
                              hipStream_t stream) {
    const float* pred = (const float*)d_in[0];
    const float* gt   = (const float*)d_in[1];
    float* out        = (float*)d_out;

    const size_t PTS_BYTES   = (size_t)8 * NPTS * sizeof(float4);   // 524288
    const size_t QLOSS_BYTES = (size_t)8 * NPTS * sizeof(float);    // 131072
    const size_t LIST_BYTES  = (size_t)LISTCAP * sizeof(unsigned);  // 131072
    const size_t NEED = PTS_BYTES + QLOSS_BYTES + LIST_BYTES + 64;

    if (ws_size >= NEED) {
        float4*       wsPts  = (float4*)d_ws;
        float*        qloss  = (float*)((char*)d_ws + PTS_BYTES);
        unsigned int* wsList = (unsigned int*)((char*)d_ws + PTS_BYTES + QLOSS_BYTES);
        unsigned int* wsCnt  = (unsigned int*)((char*)d_ws + PTS_BYTES + QLOSS_BYTES + LIST_BYTES);

        gtnl_bin<<<8, 1024, 0, stream>>>(pred, wsPts, wsCnt);
        gtnl_scan<<<NB, 256, 0, stream>>>(wsPts, gt, qloss, wsCnt, wsList);
        gtnl_fix<<<NB, 256, 0, stream>>>(wsPts, gt, qloss, wsCnt, wsList);
        gtnl_reduceQ<<<1, 1024, 0, stream>>>(qloss, out);
    } else {
        float* partial = (float*)d_ws;   // 512 floats
        gtnl_brute<<<512, 256, 0, stream>>>(pred, gt, partial);
        gtnl_reduceP<<<1, 512, 0, stream>>>(partial, out);
    }
}